// Round 7
// baseline (438.898 us; speedup 1.0000x reference)
//
#include <hip/hip_runtime.h>
#include <math.h>

// B=32,T=128,K=16,L=16; N=4096 tokens, 784 pixels, hidden 400. fp16 MFMA everywhere.
// Pipeline (4 launches):
//   k_enc1 : h16[4096,400] = relu(y @ W1^T + b1)  (fp16 MFMA)
//   k_ezb  : fused dw->fp16 prep + enc2 + z + base -> basep[4096,448], dwh[896,448]
//   k_dec  : fp16 MFMA GEMM + clip-free fused BCE -> lb[4096,16]
//            512 long-lived blocks, ot-loop inside, XCD-locality decode
//   k_hmm  : scaled linear fwd/bwd in registers -> gamma + xi (fused)

typedef _Float16 h8v __attribute__((ext_vector_type(8)));
typedef _Float16 h4v __attribute__((ext_vector_type(4)));
typedef _Float16 h2v __attribute__((ext_vector_type(2)));
typedef float f16v __attribute__((ext_vector_type(16)));

static __device__ __forceinline__ h4v cvt4(float a, float b, float c, float d) {
  h2v lo = __builtin_bit_cast(h2v, __builtin_amdgcn_cvt_pkrtz(a, b));
  h2v hi = __builtin_bit_cast(h2v, __builtin_amdgcn_cvt_pkrtz(c, d));
  h4v r;
  r[0] = lo[0]; r[1] = lo[1]; r[2] = hi[0]; r[3] = hi[1];
  return r;
}

// ---------------- K1: h16 = relu(y @ W1^T + b1), fp16 MFMA ----------------
#define E1ST 40
__global__ __launch_bounds__(256, 2)
void k_enc1(const float* __restrict__ y, const float* __restrict__ w1,
            const float* __restrict__ b1, _Float16* __restrict__ hout) {
  __shared__ __align__(16) _Float16 Ah[64 * E1ST];
  __shared__ __align__(16) _Float16 Bh[128 * E1ST];
  const int tid = threadIdx.x;
  const int i0 = blockIdx.x * 128;
  const int n0 = blockIdx.y * 64;
  const int wav = tid >> 6, lane = tid & 63;
  const int wn = wav >> 1, wi = wav & 1;
  const int ln = lane & 31, kg = lane >> 5;

  f16v acc[2];
#pragma unroll
  for (int j = 0; j < 2; ++j)
#pragma unroll
    for (int r = 0; r < 16; ++r) acc[j][r] = 0.f;

  const int ar = tid >> 3, ac4 = (tid & 7) * 4;

#pragma unroll 1
  for (int hc = 0; hc < 25; ++hc) {
    const int h0 = hc * 32;
    __syncthreads();
#pragma unroll
    for (int it = 0; it < 2; ++it) {
      int r = ar + 32 * it;
      float4 a = make_float4(0.f, 0.f, 0.f, 0.f);
      if (h0 + ac4 < 784) a = *(const float4*)&y[(n0 + r) * 784 + h0 + ac4];
      *(h4v*)&Ah[r * E1ST + ac4] = cvt4(a.x, a.y, a.z, a.w);
    }
#pragma unroll
    for (int it = 0; it < 4; ++it) {
      int idx = tid + it * 256;
      int r = idx >> 3, c4 = (idx & 7) * 4;
      int gi = i0 + r, gh = h0 + c4;
      float4 v = make_float4(0.f, 0.f, 0.f, 0.f);
      if (gi < 400 && gh + 3 < 784) v = *(const float4*)&w1[gi * 784 + gh];
      *(h4v*)&Bh[r * E1ST + c4] = cvt4(v.x, v.y, v.z, v.w);
    }
    __syncthreads();
#pragma unroll
    for (int kk = 0; kk < 2; ++kk) {
      const int ko = kk * 16 + kg * 8;
      h8v a  = *(const h8v*)&Ah[(wn * 32 + ln) * E1ST + ko];
      h8v b0 = *(const h8v*)&Bh[(wi * 64 + ln) * E1ST + ko];
      h8v b1v = *(const h8v*)&Bh[(wi * 64 + 32 + ln) * E1ST + ko];
      acc[0] = __builtin_amdgcn_mfma_f32_32x32x16_f16(a, b0, acc[0], 0, 0, 0);
      acc[1] = __builtin_amdgcn_mfma_f32_32x32x16_f16(a, b1v, acc[1], 0, 0, 0);
    }
  }
#pragma unroll
  for (int j = 0; j < 2; ++j) {
    const int i = i0 + wi * 64 + j * 32 + ln;
    if (i < 400) {
      const float bias = b1[i];
#pragma unroll
      for (int reg = 0; reg < 16; ++reg) {
        const int row = n0 + wn * 32 + (reg & 3) + 8 * (reg >> 2) + 4 * kg;
        hout[row * 400 + i] = (_Float16)fmaxf(acc[j][reg] + bias, 0.f);
      }
    }
  }
}

// ---------------- K2: fused dw-prep + enc2 + z + base ----------------
__global__ __launch_bounds__(256, 2)
void k_ezb(const _Float16* __restrict__ h, const float* __restrict__ w2,
           const float* __restrict__ b2, const float* __restrict__ eps,
           const float* __restrict__ dfw, const float* __restrict__ dfb,
           const float* __restrict__ dw, float* __restrict__ basep,
           _Float16* __restrict__ dwh) {
  __shared__ __align__(16) float h_lds[16 * 400];
  __shared__ float ml[16 * 32];
  __shared__ float zs[16 * 16];
  const int tid = threadIdx.x;
  const int n0 = blockIdx.x * 16;
  // dw -> fp16 padded [896,448]: this block's share = 1568 elems
  {
    const int base = blockIdx.x * 1568;
#pragma unroll
    for (int it = 0; it < 7; ++it) {
      int off = it * 256 + tid;
      if (off < 1568) {
        int idx = base + off;
        int o = idx / 448, h2 = idx - o * 448;
        float v = (o < 784 && h2 < 400) ? dw[o * 400 + h2] : 0.f;
        dwh[idx] = (_Float16)v;
      }
    }
  }
  for (int idx = tid; idx < 800; idx += 256) {
    int r = idx / 50, c8 = (idx % 50) * 8;
    h8v v = *(const h8v*)&h[(n0 + r) * 400 + c8];
#pragma unroll
    for (int e = 0; e < 8; ++e) h_lds[r * 400 + c8 + e] = (float)v[e];
  }
  __syncthreads();
#pragma unroll
  for (int it = 0; it < 2; ++it) {
    int task = tid + it * 256;
    int c = task & 31, n = task >> 5;
    float acc = 0.f;
    for (int q = 0; q < 100; ++q) {
      float4 hv = *(const float4*)&h_lds[n * 400 + q * 4];
      float4 wv = *(const float4*)&w2[c * 400 + q * 4];
      acc += hv.x * wv.x + hv.y * wv.y + hv.z * wv.z + hv.w * wv.w;
    }
    ml[n * 32 + c] = acc + b2[c];
  }
  __syncthreads();
  {
    int n = tid >> 4, l = tid & 15;
    float mu = ml[n * 32 + l], lv = ml[n * 32 + 16 + l];
    zs[n * 16 + l] = mu + eps[(n0 + n) * 16 + l] * expf(0.5f * lv);
  }
  __syncthreads();
  for (int idx = tid; idx < 7168; idx += 256) {
    int n = idx / 448, i = idx - n * 448;
    float acc = 0.f;
    if (i < 400) {
      acc = dfb[i];
#pragma unroll
      for (int q = 0; q < 4; ++q) {
        float4 zv = *(const float4*)&zs[n * 16 + q * 4];
        float4 wv = *(const float4*)&dfw[i * 32 + q * 4];
        acc += zv.x * wv.x + zv.y * wv.y + zv.z * wv.z + zv.w * wv.w;
      }
    }
    basep[(n0 + n) * 448 + i] = acc;
  }
}

// ---------------- K3: decoder GEMM fp16 MFMA + clip-free fused BCE ----------------
// grid 512 long-lived blocks (ot loop inside). XCD-locality decode: with round-robin
// block->XCD, one XCD holds {4 nt x 16 k}: L2 set = 4x(basep 229K + y 401K) + dwh ~ 3.3 MB.
#define DST 72
__global__ __launch_bounds__(256, 2)
void k_dec(const float* __restrict__ basep, const float* __restrict__ dfw,
           const _Float16* __restrict__ dwh, const float* __restrict__ decb,
           const float* __restrict__ y, float* __restrict__ lb) {
  __shared__ __align__(16) _Float16 Ah[128 * DST];
  __shared__ __align__(16) _Float16 Bh[128 * DST];
  __shared__ float wx[448];
  __shared__ float red[256];

  const int tid = threadIdx.x;
  const int w = blockIdx.x;
  const int k  = (w >> 3) & 15;
  const int nt = (w & 7) + 8 * (w >> 7);
  const int n0 = nt * 128;

  const int wav = tid >> 6, lane = tid & 63;
  const int wn = wav >> 1, wo = wav & 1;
  const int ln = lane & 31, kg = lane >> 5;

  for (int i = tid; i < 448; i += 256) wx[i] = (i < 400) ? dfw[i * 32 + 16 + k] : 0.f;

  float pr[2][16];
#pragma unroll
  for (int i = 0; i < 2; ++i)
#pragma unroll
    for (int r = 0; r < 16; ++r) pr[i][r] = 0.f;

  const int ar = tid >> 4, ac4 = (tid & 15) * 4;
  const int br = tid >> 3, bg = (tid & 7) * 8;
  const float* aptr = basep + (long)(n0 + ar) * 448 + ac4;

  float4 apf[8];
  h8v bpf[4];
#pragma unroll
  for (int it = 0; it < 8; ++it) apf[it] = *(const float4*)&aptr[(16 * it) * 448];
#pragma unroll
  for (int it = 0; it < 4; ++it)
    bpf[it] = *(const h8v*)&dwh[(br + 32 * it) * 448 + bg];

#pragma unroll 1
  for (int ot = 0; ot < 7; ++ot) {
    const int o0 = ot * 128;
    const bool full = (ot < 6);
    f16v acc[2][2];
#pragma unroll
    for (int i = 0; i < 2; ++i)
#pragma unroll
      for (int j = 0; j < 2; ++j)
#pragma unroll
        for (int r = 0; r < 16; ++r) acc[i][j][r] = 0.f;

#pragma unroll 1
    for (int hc = 0; hc < 7; ++hc) {
      const int h0 = hc * 64;
      __syncthreads();   // previous MFMA phase done with LDS
      {
        float4 wv = *(const float4*)&wx[h0 + ac4];
#pragma unroll
        for (int it = 0; it < 8; ++it) {
          int rr = ar + 16 * it;
          *(h4v*)&Ah[rr * DST + ac4] =
              cvt4(fmaxf(apf[it].x + wv.x, 0.f), fmaxf(apf[it].y + wv.y, 0.f),
                   fmaxf(apf[it].z + wv.z, 0.f), fmaxf(apf[it].w + wv.w, 0.f));
        }
      }
#pragma unroll
      for (int it = 0; it < 4; ++it)
        *(h8v*)&Bh[(br + 32 * it) * DST + bg] = bpf[it];
      __syncthreads();
      // prefetch next (ot,hc) chunk; loads stay in flight across the MFMA phase
      {
        int hc2 = hc + 1, ot2 = ot;
        if (hc2 == 7) { hc2 = 0; ot2 = ot + 1; }
        if (ot2 < 7) {
          const int hn = hc2 * 64;
          const int o0n = ot2 * 128;
#pragma unroll
          for (int it = 0; it < 8; ++it)
            apf[it] = *(const float4*)&aptr[(16 * it) * 448 + hn];
#pragma unroll
          for (int it = 0; it < 4; ++it)
            bpf[it] = *(const h8v*)&dwh[(o0n + br + 32 * it) * 448 + hn + bg];
        }
      }
#pragma unroll
      for (int kk = 0; kk < 4; ++kk) {
        const int ko = kk * 16 + kg * 8;
        h8v a0 = *(const h8v*)&Ah[(wn * 64 + ln) * DST + ko];
        h8v a1 = *(const h8v*)&Ah[(wn * 64 + 32 + ln) * DST + ko];
        h8v b0 = *(const h8v*)&Bh[(wo * 64 + ln) * DST + ko];
        h8v b1v = *(const h8v*)&Bh[(wo * 64 + 32 + ln) * DST + ko];
        if (full) {
          acc[0][0] = __builtin_amdgcn_mfma_f32_32x32x16_f16(a0, b0, acc[0][0], 0, 0, 0);
          acc[1][0] = __builtin_amdgcn_mfma_f32_32x32x16_f16(a1, b0, acc[1][0], 0, 0, 0);
          acc[0][1] = __builtin_amdgcn_mfma_f32_32x32x16_f16(a0, b1v, acc[0][1], 0, 0, 0);
          acc[1][1] = __builtin_amdgcn_mfma_f32_32x32x16_f16(a1, b1v, acc[1][1], 0, 0, 0);
        } else if (wo == 0) {
          acc[0][0] = __builtin_amdgcn_mfma_f32_32x32x16_f16(a0, b0, acc[0][0], 0, 0, 0);
          acc[1][0] = __builtin_amdgcn_mfma_f32_32x32x16_f16(a1, b0, acc[1][0], 0, 0, 0);
        }
      }
    }
    // epilogue: clip-free BCE = softplus(x) - y*x  (|logits| << 100, clip inactive)
    const int oa = o0 + wo * 64 + ln;
    const int ob = oa + 32;
    const float biasa = (oa < 784) ? decb[oa] : 0.f;
    const float biasb = (ob < 784) ? decb[ob] : 0.f;
#pragma unroll
    for (int i = 0; i < 2; ++i)
#pragma unroll
      for (int reg = 0; reg < 16; ++reg) {
        const int row = wn * 64 + i * 32 + (reg & 3) + 8 * (reg >> 2) + 4 * kg;
        float v = 0.f;
        if (oa < 784) {
          float x = acc[i][0][reg] + biasa;
          float yv = y[(n0 + row) * 784 + oa];
          v += fmaxf(x, 0.f) + __logf(1.f + __expf(-fabsf(x))) - yv * x;
        }
        if (ob < 784) {
          float x = acc[i][1][reg] + biasb;
          float yv = y[(n0 + row) * 784 + ob];
          v += fmaxf(x, 0.f) + __logf(1.f + __expf(-fabsf(x))) - yv * x;
        }
        pr[i][reg] += v;
      }
  }
  // reduce over the 32 o-columns of each half-wave, then across the two wo halves
#pragma unroll
  for (int i = 0; i < 2; ++i)
#pragma unroll
    for (int reg = 0; reg < 16; ++reg) {
      float v = pr[i][reg];
      v += __shfl_xor(v, 1, 64);
      v += __shfl_xor(v, 2, 64);
      v += __shfl_xor(v, 4, 64);
      v += __shfl_xor(v, 8, 64);
      v += __shfl_xor(v, 16, 64);
      if (ln == 0) {
        const int row = wn * 64 + i * 32 + (reg & 3) + 8 * (reg >> 2) + 4 * kg;
        red[wo * 128 + row] = v;
      }
    }
  __syncthreads();
  if (tid < 128)
    lb[(n0 + tid) * 16 + k] = -(red[tid] + red[128 + tid]) * 0.01f;
}

// ---------------- K4: HMM fwd/bwd in registers + fused gamma/xi ----------------
__global__ __launch_bounds__(256, 2)
void k_hmm(const float* __restrict__ lb, const float* __restrict__ lpi,
           const float* __restrict__ lA, float* __restrict__ out) {
  __shared__ float btl[128 * 16];
  __shared__ float ah[128 * 16];
  __shared__ float bh[128 * 16];
  __shared__ float braw[128 * 16];
  __shared__ float A_l[16 * 17];
  __shared__ float pi_l[16];
  __shared__ float sinv_s[128];
  const int tid = threadIdx.x;
  const int b = blockIdx.x;

  for (int idx = tid; idx < 512; idx += 256)
    *(float4*)&btl[idx * 4] = *(const float4*)&lb[b * 2048 + idx * 4];
  if (tid < 16) {
    const int j = tid;
    float m = -1e30f;
#pragma unroll
    for (int q = 0; q < 16; ++q) m = fmaxf(m, lA[j * 16 + q]);
    float e[16]; float s = 0.f;
#pragma unroll
    for (int q = 0; q < 16; ++q) { e[q] = expf(lA[j * 16 + q] - m); s += e[q]; }
    float inv = 1.f / s;
#pragma unroll
    for (int q = 0; q < 16; ++q) A_l[j * 17 + q] = e[q] * inv + 1e-9f;
  } else if (tid == 16) {
    float m = -1e30f;
#pragma unroll
    for (int q = 0; q < 16; ++q) m = fmaxf(m, lpi[q]);
    float e[16]; float s = 0.f;
#pragma unroll
    for (int q = 0; q < 16; ++q) { e[q] = expf(lpi[q] - m); s += e[q]; }
    float inv = 1.f / s;
#pragma unroll
    for (int q = 0; q < 16; ++q) pi_l[q] = e[q] * inv + 1e-9f;
  }
  __syncthreads();
  if (tid < 128) {
    const int t = tid;
    float v[16]; float m = -1e30f;
#pragma unroll
    for (int q = 0; q < 16; ++q) { v[q] = btl[t * 16 + q]; m = fmaxf(m, v[q]); }
#pragma unroll
    for (int q = 0; q < 16; ++q) btl[t * 16 + q] = expf(v[q] - m);
  }
  __syncthreads();
  const int lane = tid & 63;
  const int kk = lane & 15, grp = lane >> 4;
  if (tid < 64) {  // forward, state in registers
    float Ar[4];
#pragma unroll
    for (int jj = 0; jj < 4; ++jj) Ar[jj] = A_l[(grp * 4 + jj) * 17 + kk];
    float v = pi_l[kk] * btl[kk];
    float ss = v;
    ss += __shfl_xor(ss, 1, 64); ss += __shfl_xor(ss, 2, 64);
    ss += __shfl_xor(ss, 4, 64); ss += __shfl_xor(ss, 8, 64);
    float a = v * __builtin_amdgcn_rcpf(ss);
    if (grp == 0) ah[kk] = a;
    float btc = btl[16 + kk];
#pragma unroll 1
    for (int t = 1; t < 128; ++t) {
      float acc = 0.f;
#pragma unroll
      for (int jj = 0; jj < 4; ++jj)
        acc = fmaf(Ar[jj], __shfl(a, grp * 4 + jj, 64), acc);
      acc += __shfl_xor(acc, 16, 64);
      acc += __shfl_xor(acc, 32, 64);
      float btn = (t < 127) ? btl[(t + 1) * 16 + kk] : 0.f;
      float v2 = acc * btc;
      float s2 = v2;
      s2 += __shfl_xor(s2, 1, 64); s2 += __shfl_xor(s2, 2, 64);
      s2 += __shfl_xor(s2, 4, 64); s2 += __shfl_xor(s2, 8, 64);
      a = v2 * __builtin_amdgcn_rcpf(s2);
      if (grp == 0) ah[t * 16 + kk] = a;
      btc = btn;
    }
  } else if (tid < 128) {  // backward, state in registers
    float Ar[4];
#pragma unroll
    for (int q = 0; q < 4; ++q) Ar[q] = A_l[kk * 17 + grp * 4 + q];
    if (grp == 0) bh[127 * 16 + kk] = 1.f;
    float p = btl[127 * 16 + kk];
    float btc = btl[126 * 16 + kk];
#pragma unroll 1
    for (int t = 126; t >= 0; --t) {
      float acc = 0.f;
#pragma unroll
      for (int q = 0; q < 4; ++q)
        acc = fmaf(Ar[q], __shfl(p, grp * 4 + q, 64), acc);
      acc += __shfl_xor(acc, 16, 64);
      acc += __shfl_xor(acc, 32, 64);
      float btn = (t > 0) ? btl[(t - 1) * 16 + kk] : 0.f;
      float ss = acc;
      ss += __shfl_xor(ss, 1, 64); ss += __shfl_xor(ss, 2, 64);
      ss += __shfl_xor(ss, 4, 64); ss += __shfl_xor(ss, 8, 64);
      float bnorm = acc * __builtin_amdgcn_rcpf(ss);
      if (grp == 0) { braw[t * 16 + kk] = acc; bh[t * 16 + kk] = bnorm; }
      p = btc * bnorm;
      btc = btn;
    }
  }
  __syncthreads();
  if (tid < 128) {  // gamma
    const int t = tid;
    float g[16]; float s2 = 0.f;
#pragma unroll
    for (int q = 0; q < 16; ++q) { g[q] = ah[t * 16 + q] * bh[t * 16 + q]; s2 += g[q]; }
    float inv = 1.f / s2;
#pragma unroll
    for (int c = 0; c < 4; ++c) {
      float4 o;
      o.x = g[c * 4 + 0] * inv; o.y = g[c * 4 + 1] * inv;
      o.z = g[c * 4 + 2] * inv; o.w = g[c * 4 + 3] * inv;
      *(float4*)&out[(b * 128 + t) * 16 + c * 4] = o;
    }
  } else {  // xi normalizers
    const int t = tid - 128;
    if (t < 127) {
      float s2 = 0.f;
#pragma unroll
      for (int q = 0; q < 16; ++q) s2 += ah[t * 16 + q] * braw[t * 16 + q];
      sinv_s[t] = 1.f / s2;
    }
  }
  __syncthreads();
  {  // xi fused
    const int j = tid >> 4, k2 = tid & 15;
    const float Ajk = A_l[j * 17 + k2];
    float* xo = out + 65536 + b * 127 * 256;
#pragma unroll 1
    for (int t = 0; t < 127; ++t) {
      float val = ah[t * 16 + j] * Ajk *
                  (btl[(t + 1) * 16 + k2] * bh[(t + 1) * 16 + k2]) * sinv_s[t];
      xo[t * 256 + tid] = val;
    }
  }
}

extern "C" void kernel_launch(void* const* d_in, const int* in_sizes, int n_in,
                              void* d_out, int out_size, void* d_ws, size_t ws_size,
                              hipStream_t stream) {
  (void)in_sizes; (void)n_in; (void)out_size; (void)ws_size;
  const float* y   = (const float*)d_in[0];   // (4096,784)
  const float* ew1 = (const float*)d_in[1];   // (400,784)
  const float* eb1 = (const float*)d_in[2];   // (400,)
  const float* ew2 = (const float*)d_in[3];   // (32,400)
  const float* eb2 = (const float*)d_in[4];   // (32,)
  const float* dfw = (const float*)d_in[5];   // (400,32)
  const float* dfb = (const float*)d_in[6];   // (400,)
  const float* dw  = (const float*)d_in[7];   // (784,400)
  const float* db  = (const float*)d_in[8];   // (784,)
  const float* lpi = (const float*)d_in[9];   // (16,)
  const float* lA  = (const float*)d_in[10];  // (16,16)
  const float* eps = (const float*)d_in[11];  // (4096,16)
  float* out = (float*)d_out;

  float* ws = (float*)d_ws;
  float* basep  = ws;                              // 4096*448 = 1,835,008 f
  _Float16* h16 = (_Float16*)(ws + 1835008);       // 4096*400 halves (819,200 f)
  float* lb     = ws + 1835008 + 819200;           // 65,536 f
  _Float16* dwh = (_Float16*)(lb + 65536);         // 896*448 halves ~11.7 MB total

  k_enc1<<<dim3(4, 64), 256, 0, stream>>>(y, ew1, eb1, h16);
  k_ezb<<<256, 256, 0, stream>>>(h16, ew2, eb2, eps, dfw, dfb, dw, basep, dwh);
  k_dec<<<512, 256, 0, stream>>>(basep, dfw, dwh, db, y, lb);
  k_hmm<<<32, 256, 0, stream>>>(lb, lpi, lA, out);
}

// Round 8
// 426.586 us; speedup vs baseline: 1.0289x; 1.0289x over previous
//
#include <hip/hip_runtime.h>
#include <math.h>

// B=32,T=128,K=16,L=16; N=4096 tokens, 784 pixels, hidden 400. fp16 MFMA everywhere.
// Pipeline (4 launches):
//   k_enc1 : h16[4096,400] = relu(y @ W1^T + b1)  (fp16 MFMA)
//   k_ezb  : fused dw->fp16 prep + enc2 + z + base -> basep[4096,448], dwh[896,448]
//   k_dec  : fp16 MFMA GEMM + clip-free fused BCE -> lb[4096,16]
//            1024 blocks (64-row n-tiles) -> 4 blocks/CU for phase overlap
//   k_hmm  : scaled linear fwd/bwd in registers -> gamma + xi (fused)

typedef _Float16 h8v __attribute__((ext_vector_type(8)));
typedef _Float16 h4v __attribute__((ext_vector_type(4)));
typedef _Float16 h2v __attribute__((ext_vector_type(2)));
typedef float f16v __attribute__((ext_vector_type(16)));

static __device__ __forceinline__ h4v cvt4(float a, float b, float c, float d) {
  h2v lo = __builtin_bit_cast(h2v, __builtin_amdgcn_cvt_pkrtz(a, b));
  h2v hi = __builtin_bit_cast(h2v, __builtin_amdgcn_cvt_pkrtz(c, d));
  h4v r;
  r[0] = lo[0]; r[1] = lo[1]; r[2] = hi[0]; r[3] = hi[1];
  return r;
}

// ---------------- K1: h16 = relu(y @ W1^T + b1), fp16 MFMA ----------------
#define E1ST 40
__global__ __launch_bounds__(256, 2)
void k_enc1(const float* __restrict__ y, const float* __restrict__ w1,
            const float* __restrict__ b1, _Float16* __restrict__ hout) {
  __shared__ __align__(16) _Float16 Ah[64 * E1ST];
  __shared__ __align__(16) _Float16 Bh[128 * E1ST];
  const int tid = threadIdx.x;
  const int i0 = blockIdx.x * 128;
  const int n0 = blockIdx.y * 64;
  const int wav = tid >> 6, lane = tid & 63;
  const int wn = wav >> 1, wi = wav & 1;
  const int ln = lane & 31, kg = lane >> 5;

  f16v acc[2];
#pragma unroll
  for (int j = 0; j < 2; ++j)
#pragma unroll
    for (int r = 0; r < 16; ++r) acc[j][r] = 0.f;

  const int ar = tid >> 3, ac4 = (tid & 7) * 4;

#pragma unroll 1
  for (int hc = 0; hc < 25; ++hc) {
    const int h0 = hc * 32;
    __syncthreads();
#pragma unroll
    for (int it = 0; it < 2; ++it) {
      int r = ar + 32 * it;
      float4 a = make_float4(0.f, 0.f, 0.f, 0.f);
      if (h0 + ac4 < 784) a = *(const float4*)&y[(n0 + r) * 784 + h0 + ac4];
      *(h4v*)&Ah[r * E1ST + ac4] = cvt4(a.x, a.y, a.z, a.w);
    }
#pragma unroll
    for (int it = 0; it < 4; ++it) {
      int idx = tid + it * 256;
      int r = idx >> 3, c4 = (idx & 7) * 4;
      int gi = i0 + r, gh = h0 + c4;
      float4 v = make_float4(0.f, 0.f, 0.f, 0.f);
      if (gi < 400 && gh + 3 < 784) v = *(const float4*)&w1[gi * 784 + gh];
      *(h4v*)&Bh[r * E1ST + c4] = cvt4(v.x, v.y, v.z, v.w);
    }
    __syncthreads();
#pragma unroll
    for (int kk = 0; kk < 2; ++kk) {
      const int ko = kk * 16 + kg * 8;
      h8v a  = *(const h8v*)&Ah[(wn * 32 + ln) * E1ST + ko];
      h8v b0 = *(const h8v*)&Bh[(wi * 64 + ln) * E1ST + ko];
      h8v b1v = *(const h8v*)&Bh[(wi * 64 + 32 + ln) * E1ST + ko];
      acc[0] = __builtin_amdgcn_mfma_f32_32x32x16_f16(a, b0, acc[0], 0, 0, 0);
      acc[1] = __builtin_amdgcn_mfma_f32_32x32x16_f16(a, b1v, acc[1], 0, 0, 0);
    }
  }
#pragma unroll
  for (int j = 0; j < 2; ++j) {
    const int i = i0 + wi * 64 + j * 32 + ln;
    if (i < 400) {
      const float bias = b1[i];
#pragma unroll
      for (int reg = 0; reg < 16; ++reg) {
        const int row = n0 + wn * 32 + (reg & 3) + 8 * (reg >> 2) + 4 * kg;
        hout[row * 400 + i] = (_Float16)fmaxf(acc[j][reg] + bias, 0.f);
      }
    }
  }
}

// ---------------- K2: fused dw-prep + enc2 + z + base ----------------
__global__ __launch_bounds__(256, 2)
void k_ezb(const _Float16* __restrict__ h, const float* __restrict__ w2,
           const float* __restrict__ b2, const float* __restrict__ eps,
           const float* __restrict__ dfw, const float* __restrict__ dfb,
           const float* __restrict__ dw, float* __restrict__ basep,
           _Float16* __restrict__ dwh) {
  __shared__ __align__(16) float h_lds[16 * 400];
  __shared__ float ml[16 * 32];
  __shared__ float zs[16 * 16];
  const int tid = threadIdx.x;
  const int n0 = blockIdx.x * 16;
  // dw -> fp16 padded [896,448]: this block's share = 1568 elems
  {
    const int base = blockIdx.x * 1568;
#pragma unroll
    for (int it = 0; it < 7; ++it) {
      int off = it * 256 + tid;
      if (off < 1568) {
        int idx = base + off;
        int o = idx / 448, h2 = idx - o * 448;
        float v = (o < 784 && h2 < 400) ? dw[o * 400 + h2] : 0.f;
        dwh[idx] = (_Float16)v;
      }
    }
  }
  for (int idx = tid; idx < 800; idx += 256) {
    int r = idx / 50, c8 = (idx % 50) * 8;
    h8v v = *(const h8v*)&h[(n0 + r) * 400 + c8];
#pragma unroll
    for (int e = 0; e < 8; ++e) h_lds[r * 400 + c8 + e] = (float)v[e];
  }
  __syncthreads();
#pragma unroll
  for (int it = 0; it < 2; ++it) {
    int task = tid + it * 256;
    int c = task & 31, n = task >> 5;
    float acc = 0.f;
    for (int q = 0; q < 100; ++q) {
      float4 hv = *(const float4*)&h_lds[n * 400 + q * 4];
      float4 wv = *(const float4*)&w2[c * 400 + q * 4];
      acc += hv.x * wv.x + hv.y * wv.y + hv.z * wv.z + hv.w * wv.w;
    }
    ml[n * 32 + c] = acc + b2[c];
  }
  __syncthreads();
  {
    int n = tid >> 4, l = tid & 15;
    float mu = ml[n * 32 + l], lv = ml[n * 32 + 16 + l];
    zs[n * 16 + l] = mu + eps[(n0 + n) * 16 + l] * expf(0.5f * lv);
  }
  __syncthreads();
  for (int idx = tid; idx < 7168; idx += 256) {
    int n = idx / 448, i = idx - n * 448;
    float acc = 0.f;
    if (i < 400) {
      acc = dfb[i];
#pragma unroll
      for (int q = 0; q < 4; ++q) {
        float4 zv = *(const float4*)&zs[n * 16 + q * 4];
        float4 wv = *(const float4*)&dfw[i * 32 + q * 4];
        acc += zv.x * wv.x + zv.y * wv.y + zv.z * wv.z + zv.w * wv.w;
      }
    }
    basep[(n0 + n) * 448 + i] = acc;
  }
}

// ---------------- K3: decoder GEMM fp16 MFMA + clip-free fused BCE ----------------
// 1024 blocks (k=bx 0..15, nt=by 0..63, 64-row n-tiles), ot-loop inside.
// ~30 KB LDS, ~<=128 VGPR -> 4 blocks/CU: phase overlap across blocks hides barrier drains.
#define DST 72
__global__ __launch_bounds__(256, 4)
void k_dec(const float* __restrict__ basep, const float* __restrict__ dfw,
           const _Float16* __restrict__ dwh, const float* __restrict__ decb,
           const float* __restrict__ y, float* __restrict__ lb) {
  __shared__ __align__(16) _Float16 Ah[64 * DST];
  __shared__ __align__(16) _Float16 Bh[128 * DST];
  __shared__ float wx[448];
  __shared__ float red[128];

  const int tid = threadIdx.x;
  const int k  = blockIdx.x;
  const int n0 = blockIdx.y * 64;

  const int wav = tid >> 6, lane = tid & 63;
  const int wn = wav >> 1, wo = wav & 1;   // wave covers rows wn*32.., cols wo*64..
  const int ln = lane & 31, kg = lane >> 5;

  for (int i = tid; i < 448; i += 256) wx[i] = (i < 400) ? dfw[i * 32 + 16 + k] : 0.f;

  float pr[16];
#pragma unroll
  for (int r = 0; r < 16; ++r) pr[r] = 0.f;

  const int ar = tid >> 4, ac4 = (tid & 15) * 4;  // A: 64 rows x 16 f4, 4/thread
  const int br = tid >> 3, bg = (tid & 7) * 8;    // B: 128 rows x 8 x8, 4/thread
  const float* aptr = basep + (long)(n0 + ar) * 448 + ac4;

  float4 apf[4];
  h8v bpf[4];
#pragma unroll
  for (int it = 0; it < 4; ++it) apf[it] = *(const float4*)&aptr[(16 * it) * 448];
#pragma unroll
  for (int it = 0; it < 4; ++it)
    bpf[it] = *(const h8v*)&dwh[(br + 32 * it) * 448 + bg];

#pragma unroll 1
  for (int ot = 0; ot < 7; ++ot) {
    const int o0 = ot * 128;
    const bool full = (ot < 6);
    f16v acc[2];
#pragma unroll
    for (int j = 0; j < 2; ++j)
#pragma unroll
      for (int r = 0; r < 16; ++r) acc[j][r] = 0.f;

#pragma unroll 1
    for (int hc = 0; hc < 7; ++hc) {
      const int h0 = hc * 64;
      __syncthreads();   // previous MFMA phase done with LDS
      {
        float4 wv = *(const float4*)&wx[h0 + ac4];
#pragma unroll
        for (int it = 0; it < 4; ++it) {
          int rr = ar + 16 * it;
          *(h4v*)&Ah[rr * DST + ac4] =
              cvt4(fmaxf(apf[it].x + wv.x, 0.f), fmaxf(apf[it].y + wv.y, 0.f),
                   fmaxf(apf[it].z + wv.z, 0.f), fmaxf(apf[it].w + wv.w, 0.f));
        }
      }
#pragma unroll
      for (int it = 0; it < 4; ++it)
        *(h8v*)&Bh[(br + 32 * it) * DST + bg] = bpf[it];
      __syncthreads();
      // prefetch next (ot,hc) chunk; loads stay in flight across the MFMA phase
      {
        int hc2 = hc + 1, ot2 = ot;
        if (hc2 == 7) { hc2 = 0; ot2 = ot + 1; }
        if (ot2 < 7) {
          const int hn = hc2 * 64;
          const int o0n = ot2 * 128;
#pragma unroll
          for (int it = 0; it < 4; ++it)
            apf[it] = *(const float4*)&aptr[(16 * it) * 448 + hn];
#pragma unroll
          for (int it = 0; it < 4; ++it)
            bpf[it] = *(const h8v*)&dwh[(o0n + br + 32 * it) * 448 + hn + bg];
        }
      }
#pragma unroll
      for (int kk = 0; kk < 4; ++kk) {
        const int ko = kk * 16 + kg * 8;
        h8v a  = *(const h8v*)&Ah[(wn * 32 + ln) * DST + ko];
        h8v b0 = *(const h8v*)&Bh[(wo * 64 + ln) * DST + ko];
        h8v b1v = *(const h8v*)&Bh[(wo * 64 + 32 + ln) * DST + ko];
        if (full) {
          acc[0] = __builtin_amdgcn_mfma_f32_32x32x16_f16(a, b0, acc[0], 0, 0, 0);
          acc[1] = __builtin_amdgcn_mfma_f32_32x32x16_f16(a, b1v, acc[1], 0, 0, 0);
        } else if (wo == 0) {
          acc[0] = __builtin_amdgcn_mfma_f32_32x32x16_f16(a, b0, acc[0], 0, 0, 0);
        }
      }
    }
    // epilogue: clip-free BCE = softplus(x) - y*x  (|logits| << 100, clip inactive)
    const int oa = o0 + wo * 64 + ln;
    const int ob = oa + 32;
    const float biasa = (oa < 784) ? decb[oa] : 0.f;
    const float biasb = (ob < 784) ? decb[ob] : 0.f;
#pragma unroll
    for (int reg = 0; reg < 16; ++reg) {
      const int row = wn * 32 + (reg & 3) + 8 * (reg >> 2) + 4 * kg;
      float v = 0.f;
      if (oa < 784) {
        float x = acc[0][reg] + biasa;
        float yv = y[(n0 + row) * 784 + oa];
        v += fmaxf(x, 0.f) + __logf(1.f + __expf(-fabsf(x))) - yv * x;
      }
      if (ob < 784) {
        float x = acc[1][reg] + biasb;
        float yv = y[(n0 + row) * 784 + ob];
        v += fmaxf(x, 0.f) + __logf(1.f + __expf(-fabsf(x))) - yv * x;
      }
      pr[reg] += v;
    }
  }
  // reduce over the 32 o-columns of each half-wave, then across the two wo halves
#pragma unroll
  for (int reg = 0; reg < 16; ++reg) {
    float v = pr[reg];
    v += __shfl_xor(v, 1, 64);
    v += __shfl_xor(v, 2, 64);
    v += __shfl_xor(v, 4, 64);
    v += __shfl_xor(v, 8, 64);
    v += __shfl_xor(v, 16, 64);
    if (ln == 0) {
      const int row = wn * 32 + (reg & 3) + 8 * (reg >> 2) + 4 * kg;
      red[wo * 64 + row] = v;
    }
  }
  __syncthreads();
  if (tid < 64)
    lb[(n0 + tid) * 16 + k] = -(red[tid] + red[64 + tid]) * 0.01f;
}

// ---------------- K4: HMM fwd/bwd in registers + fused gamma/xi ----------------
__global__ __launch_bounds__(256, 2)
void k_hmm(const float* __restrict__ lb, const float* __restrict__ lpi,
           const float* __restrict__ lA, float* __restrict__ out) {
  __shared__ float btl[128 * 16];
  __shared__ float ah[128 * 16];
  __shared__ float bh[128 * 16];
  __shared__ float braw[128 * 16];
  __shared__ float A_l[16 * 17];
  __shared__ float pi_l[16];
  __shared__ float sinv_s[128];
  const int tid = threadIdx.x;
  const int b = blockIdx.x;

  for (int idx = tid; idx < 512; idx += 256)
    *(float4*)&btl[idx * 4] = *(const float4*)&lb[b * 2048 + idx * 4];
  if (tid < 16) {
    const int j = tid;
    float m = -1e30f;
#pragma unroll
    for (int q = 0; q < 16; ++q) m = fmaxf(m, lA[j * 16 + q]);
    float e[16]; float s = 0.f;
#pragma unroll
    for (int q = 0; q < 16; ++q) { e[q] = expf(lA[j * 16 + q] - m); s += e[q]; }
    float inv = 1.f / s;
#pragma unroll
    for (int q = 0; q < 16; ++q) A_l[j * 17 + q] = e[q] * inv + 1e-9f;
  } else if (tid == 16) {
    float m = -1e30f;
#pragma unroll
    for (int q = 0; q < 16; ++q) m = fmaxf(m, lpi[q]);
    float e[16]; float s = 0.f;
#pragma unroll
    for (int q = 0; q < 16; ++q) { e[q] = expf(lpi[q] - m); s += e[q]; }
    float inv = 1.f / s;
#pragma unroll
    for (int q = 0; q < 16; ++q) pi_l[q] = e[q] * inv + 1e-9f;
  }
  __syncthreads();
  if (tid < 128) {
    const int t = tid;
    float v[16]; float m = -1e30f;
#pragma unroll
    for (int q = 0; q < 16; ++q) { v[q] = btl[t * 16 + q]; m = fmaxf(m, v[q]); }
#pragma unroll
    for (int q = 0; q < 16; ++q) btl[t * 16 + q] = expf(v[q] - m);
  }
  __syncthreads();
  const int lane = tid & 63;
  const int kk = lane & 15, grp = lane >> 4;
  if (tid < 64) {  // forward, state in registers
    float Ar[4];
#pragma unroll
    for (int jj = 0; jj < 4; ++jj) Ar[jj] = A_l[(grp * 4 + jj) * 17 + kk];
    float v = pi_l[kk] * btl[kk];
    float ss = v;
    ss += __shfl_xor(ss, 1, 64); ss += __shfl_xor(ss, 2, 64);
    ss += __shfl_xor(ss, 4, 64); ss += __shfl_xor(ss, 8, 64);
    float a = v * __builtin_amdgcn_rcpf(ss);
    if (grp == 0) ah[kk] = a;
    float btc = btl[16 + kk];
#pragma unroll 1
    for (int t = 1; t < 128; ++t) {
      float acc = 0.f;
#pragma unroll
      for (int jj = 0; jj < 4; ++jj)
        acc = fmaf(Ar[jj], __shfl(a, grp * 4 + jj, 64), acc);
      acc += __shfl_xor(acc, 16, 64);
      acc += __shfl_xor(acc, 32, 64);
      float btn = (t < 127) ? btl[(t + 1) * 16 + kk] : 0.f;
      float v2 = acc * btc;
      float s2 = v2;
      s2 += __shfl_xor(s2, 1, 64); s2 += __shfl_xor(s2, 2, 64);
      s2 += __shfl_xor(s2, 4, 64); s2 += __shfl_xor(s2, 8, 64);
      a = v2 * __builtin_amdgcn_rcpf(s2);
      if (grp == 0) ah[t * 16 + kk] = a;
      btc = btn;
    }
  } else if (tid < 128) {  // backward, state in registers
    float Ar[4];
#pragma unroll
    for (int q = 0; q < 4; ++q) Ar[q] = A_l[kk * 17 + grp * 4 + q];
    if (grp == 0) bh[127 * 16 + kk] = 1.f;
    float p = btl[127 * 16 + kk];
    float btc = btl[126 * 16 + kk];
#pragma unroll 1
    for (int t = 126; t >= 0; --t) {
      float acc = 0.f;
#pragma unroll
      for (int q = 0; q < 4; ++q)
        acc = fmaf(Ar[q], __shfl(p, grp * 4 + q, 64), acc);
      acc += __shfl_xor(acc, 16, 64);
      acc += __shfl_xor(acc, 32, 64);
      float btn = (t > 0) ? btl[(t - 1) * 16 + kk] : 0.f;
      float ss = acc;
      ss += __shfl_xor(ss, 1, 64); ss += __shfl_xor(ss, 2, 64);
      ss += __shfl_xor(ss, 4, 64); ss += __shfl_xor(ss, 8, 64);
      float bnorm = acc * __builtin_amdgcn_rcpf(ss);
      if (grp == 0) { braw[t * 16 + kk] = acc; bh[t * 16 + kk] = bnorm; }
      p = btc * bnorm;
      btc = btn;
    }
  }
  __syncthreads();
  if (tid < 128) {  // gamma
    const int t = tid;
    float g[16]; float s2 = 0.f;
#pragma unroll
    for (int q = 0; q < 16; ++q) { g[q] = ah[t * 16 + q] * bh[t * 16 + q]; s2 += g[q]; }
    float inv = 1.f / s2;
#pragma unroll
    for (int c = 0; c < 4; ++c) {
      float4 o;
      o.x = g[c * 4 + 0] * inv; o.y = g[c * 4 + 1] * inv;
      o.z = g[c * 4 + 2] * inv; o.w = g[c * 4 + 3] * inv;
      *(float4*)&out[(b * 128 + t) * 16 + c * 4] = o;
    }
  } else {  // xi normalizers
    const int t = tid - 128;
    if (t < 127) {
      float s2 = 0.f;
#pragma unroll
      for (int q = 0; q < 16; ++q) s2 += ah[t * 16 + q] * braw[t * 16 + q];
      sinv_s[t] = 1.f / s2;
    }
  }
  __syncthreads();
  {  // xi fused
    const int j = tid >> 4, k2 = tid & 15;
    const float Ajk = A_l[j * 17 + k2];
    float* xo = out + 65536 + b * 127 * 256;
#pragma unroll 1
    for (int t = 0; t < 127; ++t) {
      float val = ah[t * 16 + j] * Ajk *
                  (btl[(t + 1) * 16 + k2] * bh[(t + 1) * 16 + k2]) * sinv_s[t];
      xo[t * 256 + tid] = val;
    }
  }
}

extern "C" void kernel_launch(void* const* d_in, const int* in_sizes, int n_in,
                              void* d_out, int out_size, void* d_ws, size_t ws_size,
                              hipStream_t stream) {
  (void)in_sizes; (void)n_in; (void)out_size; (void)ws_size;
  const float* y   = (const float*)d_in[0];   // (4096,784)
  const float* ew1 = (const float*)d_in[1];   // (400,784)
  const float* eb1 = (const float*)d_in[2];   // (400,)
  const float* ew2 = (const float*)d_in[3];   // (32,400)
  const float* eb2 = (const float*)d_in[4];   // (32,)
  const float* dfw = (const float*)d_in[5];   // (400,32)
  const float* dfb = (const float*)d_in[6];   // (400,)
  const float* dw  = (const float*)d_in[7];   // (784,400)
  const float* db  = (const float*)d_in[8];   // (784,)
  const float* lpi = (const float*)d_in[9];   // (16,)
  const float* lA  = (const float*)d_in[10];  // (16,16)
  const float* eps = (const float*)d_in[11];  // (4096,16)
  float* out = (float*)d_out;

  float* ws = (float*)d_ws;
  float* basep  = ws;                              // 4096*448 = 1,835,008 f
  _Float16* h16 = (_Float16*)(ws + 1835008);       // 4096*400 halves (819,200 f)
  float* lb     = ws + 1835008 + 819200;           // 65,536 f
  _Float16* dwh = (_Float16*)(lb + 65536);         // 896*448 halves ~11.7 MB total

  k_enc1<<<dim3(4, 64), 256, 0, stream>>>(y, ew1, eb1, h16);
  k_ezb<<<256, 256, 0, stream>>>(h16, ew2, eb2, eps, dfw, dfb, dw, basep, dwh);
  k_dec<<<dim3(16, 64), 256, 0, stream>>>(basep, dfw, dwh, db, y, lb);
  k_hmm<<<32, 256, 0, stream>>>(lb, lpi, lA, out);
}